// Round 8
// baseline (396.400 us; speedup 1.0000x reference)
//
#include <hip/hip_runtime.h>

// GCN: 2x (h@W -> symmetric-norm neighbor aggregation +bias, relu) -> h@Wl+bl
// N=100000, E=1600000, D=H=64, C=16, fp32 (no fp32 MFMA -> VALU).
// Round 6: transform via scalar-broadcast GEMM — W column in 64 VGPRs (loaded
// once, coalesced), x rows coalesced per-lane, k-broadcast via v_readlane ->
// SGPR-operand FMA. No LDS, no in-loop loads to hoist, bounded ~92 VGPR.
// Rounds 3-5 all spilled (VGPR cap 64/128 vs scheduler-hoisted demand ~200).

#define WS_ALIGN 256
#define BSHIFT 8            // 256 nodes per bucket
#define MAXBUCK 512         // n=100000 -> nbuck=391

// ---------------- CSR build ----------------

__global__ void k_count(const int* __restrict__ dst, int* __restrict__ cnts, int e) {
    for (int i = blockIdx.x * blockDim.x + threadIdx.x; i < e; i += gridDim.x * blockDim.x)
        atomicAdd(&cnts[dst[i]], 1);
}

// exclusive scan of cnts -> offs (partial), per-block totals -> bsums, inv = rsqrt(cnt+1)
__global__ void k_scan1(const int* __restrict__ cnts, int* __restrict__ offs,
                        int* __restrict__ bsums, float* __restrict__ inv, int n) {
    __shared__ int tmp[256];
    int t = threadIdx.x;
    int i = blockIdx.x * 256 + t;
    int v = (i < n) ? cnts[i] : 0;
    if (i < n) inv[i] = rsqrtf((float)v + 1.0f);
    tmp[t] = v;
    __syncthreads();
    int x = v;
    #pragma unroll
    for (int d = 1; d < 256; d <<= 1) {
        int y = (t >= d) ? tmp[t - d] : 0;
        __syncthreads();
        x += y;
        tmp[t] = x;
        __syncthreads();
    }
    if (i < n) offs[i] = x - v;                 // exclusive (within block)
    if (t == 255) bsums[blockIdx.x] = x;        // block total
}

__global__ void k_scan2(int* bsums, int nb) {
    if (threadIdx.x == 0 && blockIdx.x == 0) {
        int run = 0;
        for (int b = 0; b < nb; ++b) { int v = bsums[b]; bsums[b] = run; run += v; }
    }
}

// add block prefixes; also emit bucket base cursors (bucket = 256 nodes = 1 scan block)
__global__ void k_scan3(int* __restrict__ offs, const int* __restrict__ bsums,
                        int* __restrict__ gcursor, int n) {
    int i = blockIdx.x * 256 + threadIdx.x;
    if (i < n) {
        int v = offs[i] + bsums[i >> 8];
        offs[i] = v;
        if ((i & 255) == 0) gcursor[i >> 8] = v;
    }
}

// Phase A: partition (src,dst) pairs into bucket-contiguous regions of bpairs.
__global__ void k_partition(const int* __restrict__ src, const int* __restrict__ dst,
                            int* __restrict__ gcursor, int2* __restrict__ bpairs,
                            int e, int nbuck) {
    __shared__ int hist[MAXBUCK];
    __shared__ int lbase[MAXBUCK];
    const int CH = 4096;
    int base = blockIdx.x * CH;
    int end = base + CH; if (end > e) end = e;
    for (int t = threadIdx.x; t < nbuck; t += blockDim.x) hist[t] = 0;
    __syncthreads();
    for (int i = base + threadIdx.x; i < end; i += blockDim.x)
        atomicAdd(&hist[dst[i] >> BSHIFT], 1);
    __syncthreads();
    for (int t = threadIdx.x; t < nbuck; t += blockDim.x) {
        int c = hist[t];
        lbase[t] = (c > 0) ? atomicAdd(&gcursor[t], c) : 0;
        hist[t] = 0;                              // reuse as local cursor
    }
    __syncthreads();
    for (int i = base + threadIdx.x; i < end; i += blockDim.x) {
        int s = src[i], d = dst[i];
        int b = d >> BSHIFT;
        int p = lbase[b] + atomicAdd(&hist[b], 1);
        bpairs[p] = make_int2(s, d);
    }
}

// Phase B: exact CSR scatter within each bucket (LDS cursors, L1-hot writes).
__global__ void k_scatter2(const int2* __restrict__ bpairs, const int* __restrict__ offs,
                           int* __restrict__ ssrc, int n, int e) {
    __shared__ int lcur[1 << BSHIFT];
    int b = blockIdx.x;
    int node0 = b << BSHIFT;
    int node1 = node0 + (1 << BSHIFT);
    int lo = (node0 < n) ? offs[node0] : e;
    int hi = (node1 < n) ? offs[node1] : e;
    for (int t = threadIdx.x; t < (1 << BSHIFT); t += blockDim.x) lcur[t] = 0;
    __syncthreads();
    for (int i = lo + threadIdx.x; i < hi; i += blockDim.x) {
        int2 p = bpairs[i];
        int pos = offs[p.y] + atomicAdd(&lcur[p.y & ((1 << BSHIFT) - 1)], 1);
        ssrc[pos] = p.x;
    }
}

// ---------------- transform: t'[row][:] = (in[row][:] @ W) * inv[row] ----------------
// Scalar-broadcast GEMM. Wave = 8 rows x 64 cols; lane = output column.
// w[64] = W[:, lane] in VGPRs (loaded once, coalesced). xr[r] = in[row][lane]
// (coalesced). Inner loop: readlane(xr[r], k) -> SGPR, fmaf(s, w[k], acc[r]).
// No LDS, no loads inside the k-loop => register demand statically ~92.

__global__ void __launch_bounds__(256, 2)
k_transform(const float* __restrict__ in, const float* __restrict__ W,
            const float* __restrict__ inv, float* __restrict__ out, int n) {
    const int lane = threadIdx.x & 63;
    const int wid = blockIdx.x * 4 + (threadIdx.x >> 6);
    const int nw = gridDim.x * 4;

    float w[64];
    #pragma unroll
    for (int k = 0; k < 64; ++k) w[k] = W[k * 64 + lane];

    for (int base = wid * 8; base < n; base += nw * 8) {
        float xr[8];
        #pragma unroll
        for (int r = 0; r < 8; ++r) {
            int row = base + r;                               // wave-uniform
            xr[r] = (row < n) ? in[(size_t)row * 64 + lane] : 0.f;
        }
        float acc[8] = {0.f, 0.f, 0.f, 0.f, 0.f, 0.f, 0.f, 0.f};
        #pragma unroll
        for (int r = 0; r < 8; ++r) {
            int xb = __float_as_int(xr[r]);
            #pragma unroll
            for (int k = 0; k < 64; ++k) {
                float s = __int_as_float(__builtin_amdgcn_readlane(xb, k));
                acc[r] = fmaf(s, w[k], acc[r]);
            }
        }
        #pragma unroll
        for (int r = 0; r < 8; ++r) {
            int row = base + r;
            if (row < n)
                out[(size_t)row * 64 + lane] = acc[r] * inv[row];
        }
    }
}

// ---------------- aggregation: out[d] = (sum_{e} t'[src] + t'[d]) * inv[d] + b ----------------
// t' already carries inv[src]. One coalesced index load per 64 edges,
// readlane broadcast (SGPR base) -> coalesced row gather. ~1 VMEM instr/edge.

__global__ void __launch_bounds__(256, 4)
k_aggregate(const float* __restrict__ t, const int* __restrict__ ssrc,
            const int* __restrict__ offs, const int* __restrict__ cnts,
            const float* __restrict__ inv, const float* __restrict__ b,
            float* __restrict__ out, int n, int do_relu) {
    const int lane = threadIdx.x & 63;
    const int wid = blockIdx.x * (blockDim.x >> 6) + (threadIdx.x >> 6);
    const int nw = gridDim.x * (blockDim.x >> 6);
    const float bj = b[lane];
    for (int node = wid; node < n; node += nw) {
        const int start = offs[node];
        const int cnt = cnts[node];
        float acc = 0.f;
        for (int be = 0; be < cnt; be += 64) {
            int m = cnt - be; if (m > 64) m = 64;
            int myidx = (lane < m) ? ssrc[start + be + lane] : 0;
            int j = 0;
            for (; j + 4 <= m; j += 4) {
                int s0 = __builtin_amdgcn_readlane(myidx, j + 0);
                int s1 = __builtin_amdgcn_readlane(myidx, j + 1);
                int s2 = __builtin_amdgcn_readlane(myidx, j + 2);
                int s3 = __builtin_amdgcn_readlane(myidx, j + 3);
                float v0 = t[(size_t)s0 * 64 + lane];
                float v1 = t[(size_t)s1 * 64 + lane];
                float v2 = t[(size_t)s2 * 64 + lane];
                float v3 = t[(size_t)s3 * 64 + lane];
                acc += (v0 + v1) + (v2 + v3);
            }
            for (; j < m; ++j) {
                int s = __builtin_amdgcn_readlane(myidx, j);
                acc += t[(size_t)s * 64 + lane];
            }
        }
        float res = fmaf(acc + t[(size_t)node * 64 + lane], inv[node], bj);
        if (do_relu) res = fmaxf(res, 0.f);
        out[(size_t)node * 64 + lane] = res;
    }
}

// ---------------- final projection: out[n][16] = h[n][64] @ Wl[64][16] + bl ----------------

__global__ void k_final(const float* __restrict__ h, const float* __restrict__ Wl,
                        const float* __restrict__ bl, float* __restrict__ out, int n) {
    __shared__ float Ws[64 * 16];
    for (int i = threadIdx.x; i < 64 * 16; i += blockDim.x) Ws[i] = Wl[i];
    __syncthreads();
    const int lane = threadIdx.x & 63;
    const int r = lane >> 4, c = lane & 15;
    const int wid = blockIdx.x * (blockDim.x >> 6) + (threadIdx.x >> 6);
    const int nw = gridDim.x * (blockDim.x >> 6);
    const float blc = bl[c];
    for (int base = wid * 4; base < n; base += nw * 4) {
        int row = base + r;
        if (row < n) {
            float acc = blc;
            #pragma unroll
            for (int kk = 0; kk < 16; ++kk) {
                float4 xv = *reinterpret_cast<const float4*>(h + (size_t)row * 64 + kk * 4);
                acc = fmaf(xv.x, Ws[(kk * 4 + 0) * 16 + c],
                      fmaf(xv.y, Ws[(kk * 4 + 1) * 16 + c],
                      fmaf(xv.z, Ws[(kk * 4 + 2) * 16 + c],
                      fmaf(xv.w, Ws[(kk * 4 + 3) * 16 + c], acc))));
            }
            out[(size_t)row * 16 + c] = acc;
        }
    }
}

// ---------------- host ----------------

extern "C" void kernel_launch(void* const* d_in, const int* in_sizes, int n_in,
                              void* d_out, int out_size, void* d_ws, size_t ws_size,
                              hipStream_t stream) {
    const float* x  = (const float*)d_in[0];
    const int*   ei = (const int*)d_in[1];
    const float* W1 = (const float*)d_in[2];
    const float* b1 = (const float*)d_in[3];
    const float* W2 = (const float*)d_in[4];
    const float* b2 = (const float*)d_in[5];
    const float* Wl = (const float*)d_in[6];
    const float* bl = (const float*)d_in[7];
    float* out = (float*)d_out;

    const int n = in_sizes[0] / 64;
    const int e = in_sizes[1] / 2;
    const int* src = ei;
    const int* dst = ei + e;
    const int nbuck = (n + (1 << BSHIFT) - 1) >> BSHIFT;   // 391 for n=100000

    char* ws = (char*)d_ws;
    size_t off = 0;
    auto alloc = [&](size_t bytes) -> void* {
        void* p = ws + off;
        off += (bytes + (WS_ALIGN - 1)) & ~((size_t)WS_ALIGN - 1);
        return p;
    };
    const int nb = (n + 255) / 256;
    int*   cnts    = (int*)alloc((size_t)n * 4);
    int*   offs    = (int*)alloc((size_t)n * 4);
    int*   bsums   = (int*)alloc((size_t)nb * 4);
    int*   gcursor = (int*)alloc((size_t)nbuck * 4);
    float* inv     = (float*)alloc((size_t)n * 4);
    int*   ssrc    = (int*)alloc((size_t)e * 4);
    float* bufA    = (float*)alloc((size_t)n * 64 * 4);
    float* bufB    = (float*)alloc((size_t)n * 64 * 4);
    int2*  bpairs  = (int2*)bufA;   // alias: bufA unused until transforms

    hipMemsetAsync(cnts, 0, (size_t)n * 4, stream);

    k_count<<<2048, 256, 0, stream>>>(dst, cnts, e);
    k_scan1<<<nb, 256, 0, stream>>>(cnts, offs, bsums, inv, n);
    k_scan2<<<1, 64, 0, stream>>>(bsums, nb);
    k_scan3<<<nb, 256, 0, stream>>>(offs, bsums, gcursor, n);
    k_partition<<<(e + 4095) / 4096, 256, 0, stream>>>(src, dst, gcursor, bpairs, e, nbuck);
    k_scatter2<<<nbuck, 256, 0, stream>>>(bpairs, offs, ssrc, n, e);

    // layer 1: t' = (x@W1)*inv ; h1 = relu((sum t'[src] + t'[d])*inv[d] + b1)
    k_transform<<<1024, 256, 0, stream>>>(x, W1, inv, bufA, n);
    k_aggregate<<<2048, 256, 0, stream>>>(bufA, ssrc, offs, cnts, inv, b1, bufB, n, 1);
    // layer 2
    k_transform<<<1024, 256, 0, stream>>>(bufB, W2, inv, bufA, n);
    k_aggregate<<<2048, 256, 0, stream>>>(bufA, ssrc, offs, cnts, inv, b2, bufB, n, 1);
    // readout
    k_final<<<2048, 256, 0, stream>>>(bufB, Wl, bl, out, n);
}

// Round 9
// 298.504 us; speedup vs baseline: 1.3280x; 1.3280x over previous
//
#include <hip/hip_runtime.h>

// GCN: 2x (h@W -> symmetric-norm neighbor aggregation +bias, relu) -> h@Wl+bl
// N=100000, E=1600000, D=H=64, C=16, fp32 (no fp32 MFMA -> VALU).
// Round 9: CSR build restructured to kill k_count's 1.6M global atomics
// (65us, 50MB atomic write-amp) and the 100k-node scan:
//   bhist (bucket-level LDS hist) -> bscan (391-entry scan) -> partition
//   -> bfin (per-bucket: LDS node-count + LDS scan + offs/cnts/inv write +
//            LDS-cursor scatter). All per-node counting now in LDS.
// Transform: scalar-broadcast GEMM (readlane), no LDS, no spill (round 8).

#define WS_ALIGN 256
#define BSHIFT 8            // 256 nodes per bucket
#define MAXBUCK 512         // n=100000 -> nbuck=391

// ---------------- CSR build ----------------

// bucket-level histogram: one global atomic per (block,bucket)
__global__ void k_bhist(const int* __restrict__ dst, int* __restrict__ bhist,
                        int e, int nbuck) {
    __shared__ int hist[MAXBUCK];
    const int CH = 4096;
    int base = blockIdx.x * CH;
    int end = base + CH; if (end > e) end = e;
    for (int t = threadIdx.x; t < nbuck; t += blockDim.x) hist[t] = 0;
    __syncthreads();
    for (int i = base + threadIdx.x; i < end; i += blockDim.x)
        atomicAdd(&hist[dst[i] >> BSHIFT], 1);
    __syncthreads();
    for (int t = threadIdx.x; t < nbuck; t += blockDim.x)
        if (hist[t]) atomicAdd(&bhist[t], hist[t]);
}

// single-block exclusive scan of bucket totals -> gbase (nbuck+1), gcursor
__global__ void k_bscan(const int* __restrict__ bhist, int* __restrict__ gbase,
                        int* __restrict__ gcursor, int e, int nbuck) {
    __shared__ int tmp[MAXBUCK];
    int t = threadIdx.x;                      // blockDim = MAXBUCK
    int v = (t < nbuck) ? bhist[t] : 0;
    tmp[t] = v;
    __syncthreads();
    int x = v;
    #pragma unroll
    for (int d = 1; d < MAXBUCK; d <<= 1) {
        int y = (t >= d) ? tmp[t - d] : 0;
        __syncthreads();
        x += y;
        tmp[t] = x;
        __syncthreads();
    }
    if (t < nbuck) { gbase[t] = x - v; gcursor[t] = x - v; }
    if (t == 0) gbase[nbuck] = e;
}

// partition (src,dst) pairs into bucket-contiguous regions of bpairs
__global__ void k_partition(const int* __restrict__ src, const int* __restrict__ dst,
                            int* __restrict__ gcursor, int2* __restrict__ bpairs,
                            int e, int nbuck) {
    __shared__ int hist[MAXBUCK];
    __shared__ int lbase[MAXBUCK];
    const int CH = 4096;
    int base = blockIdx.x * CH;
    int end = base + CH; if (end > e) end = e;
    for (int t = threadIdx.x; t < nbuck; t += blockDim.x) hist[t] = 0;
    __syncthreads();
    for (int i = base + threadIdx.x; i < end; i += blockDim.x)
        atomicAdd(&hist[dst[i] >> BSHIFT], 1);
    __syncthreads();
    for (int t = threadIdx.x; t < nbuck; t += blockDim.x) {
        int c = hist[t];
        lbase[t] = (c > 0) ? atomicAdd(&gcursor[t], c) : 0;
        hist[t] = 0;                              // reuse as local cursor
    }
    __syncthreads();
    for (int i = base + threadIdx.x; i < end; i += blockDim.x) {
        int s = src[i], d = dst[i];
        int b = d >> BSHIFT;
        int p = lbase[b] + atomicAdd(&hist[b], 1);
        bpairs[p] = make_int2(s, d);
    }
}

// per-bucket finalize: node counts (LDS), 256-entry exclusive scan (LDS),
// offs/cnts/inv global write, then exact scatter with LDS cursors.
__global__ void k_bfin(const int2* __restrict__ bpairs, const int* __restrict__ gbase,
                       int* __restrict__ offs, int* __restrict__ cnts,
                       float* __restrict__ inv, int* __restrict__ ssrc, int n) {
    __shared__ int lcnt[256];
    __shared__ int tmp[256];
    __shared__ int loff[256];
    __shared__ int lcur[256];
    const int b = blockIdx.x;
    const int t = threadIdx.x;                 // blockDim = 256
    const int lo = gbase[b];
    const int hi = gbase[b + 1];
    lcnt[t] = 0; lcur[t] = 0;
    __syncthreads();
    for (int i = lo + t; i < hi; i += 256)
        atomicAdd(&lcnt[bpairs[i].y & 255], 1);
    __syncthreads();
    // exclusive scan of lcnt
    int v = lcnt[t];
    tmp[t] = v;
    __syncthreads();
    int x = v;
    #pragma unroll
    for (int d = 1; d < 256; d <<= 1) {
        int y = (t >= d) ? tmp[t - d] : 0;
        __syncthreads();
        x += y;
        tmp[t] = x;
        __syncthreads();
    }
    loff[t] = x - v;
    int node = (b << BSHIFT) + t;
    if (node < n) {
        offs[node] = lo + (x - v);
        cnts[node] = v;
        inv[node] = rsqrtf((float)v + 1.0f);
    }
    __syncthreads();
    for (int i = lo + t; i < hi; i += 256) {
        int2 p = bpairs[i];
        int l = p.y & 255;
        int pos = lo + loff[l] + atomicAdd(&lcur[l], 1);
        ssrc[pos] = p.x;
    }
}

// ---------------- transform: t'[row][:] = (in[row][:] @ W) * inv[row] ----------------
// Scalar-broadcast GEMM. Wave = 8 rows x 64 cols; lane = output column.
// w[64] = W[:, lane] in VGPRs (loaded once, coalesced). xr[r] = in[row][lane]
// (coalesced). Inner loop: readlane(xr[r], k) -> SGPR, fmaf(s, w[k], acc[r]).

__global__ void __launch_bounds__(256, 2)
k_transform(const float* __restrict__ in, const float* __restrict__ W,
            const float* __restrict__ inv, float* __restrict__ out, int n) {
    const int lane = threadIdx.x & 63;
    const int wid = blockIdx.x * 4 + (threadIdx.x >> 6);
    const int nw = gridDim.x * 4;

    float w[64];
    #pragma unroll
    for (int k = 0; k < 64; ++k) w[k] = W[k * 64 + lane];

    for (int base = wid * 8; base < n; base += nw * 8) {
        float xr[8];
        #pragma unroll
        for (int r = 0; r < 8; ++r) {
            int row = base + r;                               // wave-uniform
            xr[r] = (row < n) ? in[(size_t)row * 64 + lane] : 0.f;
        }
        float acc[8] = {0.f, 0.f, 0.f, 0.f, 0.f, 0.f, 0.f, 0.f};
        #pragma unroll
        for (int r = 0; r < 8; ++r) {
            int xb = __float_as_int(xr[r]);
            #pragma unroll
            for (int k = 0; k < 64; ++k) {
                float s = __int_as_float(__builtin_amdgcn_readlane(xb, k));
                acc[r] = fmaf(s, w[k], acc[r]);
            }
        }
        #pragma unroll
        for (int r = 0; r < 8; ++r) {
            int row = base + r;
            if (row < n)
                out[(size_t)row * 64 + lane] = acc[r] * inv[row];
        }
    }
}

// ---------------- aggregation: out[d] = (sum_{e} t'[src] + t'[d]) * inv[d] + b ----------------
// t' already carries inv[src]. One coalesced index load per 64 edges,
// readlane broadcast (SGPR base) -> coalesced row gather. ~1 VMEM instr/edge.

__global__ void __launch_bounds__(256, 4)
k_aggregate(const float* __restrict__ t, const int* __restrict__ ssrc,
            const int* __restrict__ offs, const int* __restrict__ cnts,
            const float* __restrict__ inv, const float* __restrict__ b,
            float* __restrict__ out, int n, int do_relu) {
    const int lane = threadIdx.x & 63;
    const int wid = blockIdx.x * (blockDim.x >> 6) + (threadIdx.x >> 6);
    const int nw = gridDim.x * (blockDim.x >> 6);
    const float bj = b[lane];
    for (int node = wid; node < n; node += nw) {
        const int start = offs[node];
        const int cnt = cnts[node];
        float acc = 0.f;
        for (int be = 0; be < cnt; be += 64) {
            int m = cnt - be; if (m > 64) m = 64;
            int myidx = (lane < m) ? ssrc[start + be + lane] : 0;
            int j = 0;
            for (; j + 4 <= m; j += 4) {
                int s0 = __builtin_amdgcn_readlane(myidx, j + 0);
                int s1 = __builtin_amdgcn_readlane(myidx, j + 1);
                int s2 = __builtin_amdgcn_readlane(myidx, j + 2);
                int s3 = __builtin_amdgcn_readlane(myidx, j + 3);
                float v0 = t[(size_t)s0 * 64 + lane];
                float v1 = t[(size_t)s1 * 64 + lane];
                float v2 = t[(size_t)s2 * 64 + lane];
                float v3 = t[(size_t)s3 * 64 + lane];
                acc += (v0 + v1) + (v2 + v3);
            }
            for (; j < m; ++j) {
                int s = __builtin_amdgcn_readlane(myidx, j);
                acc += t[(size_t)s * 64 + lane];
            }
        }
        float res = fmaf(acc + t[(size_t)node * 64 + lane], inv[node], bj);
        if (do_relu) res = fmaxf(res, 0.f);
        out[(size_t)node * 64 + lane] = res;
    }
}

// ---------------- final projection: out[n][16] = h[n][64] @ Wl[64][16] + bl ----------------

__global__ void k_final(const float* __restrict__ h, const float* __restrict__ Wl,
                        const float* __restrict__ bl, float* __restrict__ out, int n) {
    __shared__ float Ws[64 * 16];
    for (int i = threadIdx.x; i < 64 * 16; i += blockDim.x) Ws[i] = Wl[i];
    __syncthreads();
    const int lane = threadIdx.x & 63;
    const int r = lane >> 4, c = lane & 15;
    const int wid = blockIdx.x * (blockDim.x >> 6) + (threadIdx.x >> 6);
    const int nw = gridDim.x * (blockDim.x >> 6);
    const float blc = bl[c];
    for (int base = wid * 4; base < n; base += nw * 4) {
        int row = base + r;
        if (row < n) {
            float acc = blc;
            #pragma unroll
            for (int kk = 0; kk < 16; ++kk) {
                float4 xv = *reinterpret_cast<const float4*>(h + (size_t)row * 64 + kk * 4);
                acc = fmaf(xv.x, Ws[(kk * 4 + 0) * 16 + c],
                      fmaf(xv.y, Ws[(kk * 4 + 1) * 16 + c],
                      fmaf(xv.z, Ws[(kk * 4 + 2) * 16 + c],
                      fmaf(xv.w, Ws[(kk * 4 + 3) * 16 + c], acc))));
            }
            out[(size_t)row * 16 + c] = acc;
        }
    }
}

// ---------------- host ----------------

extern "C" void kernel_launch(void* const* d_in, const int* in_sizes, int n_in,
                              void* d_out, int out_size, void* d_ws, size_t ws_size,
                              hipStream_t stream) {
    const float* x  = (const float*)d_in[0];
    const int*   ei = (const int*)d_in[1];
    const float* W1 = (const float*)d_in[2];
    const float* b1 = (const float*)d_in[3];
    const float* W2 = (const float*)d_in[4];
    const float* b2 = (const float*)d_in[5];
    const float* Wl = (const float*)d_in[6];
    const float* bl = (const float*)d_in[7];
    float* out = (float*)d_out;

    const int n = in_sizes[0] / 64;
    const int e = in_sizes[1] / 2;
    const int* src = ei;
    const int* dst = ei + e;
    const int nbuck = (n + (1 << BSHIFT) - 1) >> BSHIFT;   // 391 for n=100000
    const int nchunk = (e + 4095) / 4096;

    char* ws = (char*)d_ws;
    size_t off = 0;
    auto alloc = [&](size_t bytes) -> void* {
        void* p = ws + off;
        off += (bytes + (WS_ALIGN - 1)) & ~((size_t)WS_ALIGN - 1);
        return p;
    };
    int*   bhist   = (int*)alloc((size_t)MAXBUCK * 4);
    int*   gbase   = (int*)alloc((size_t)(MAXBUCK + 1) * 4);
    int*   gcursor = (int*)alloc((size_t)MAXBUCK * 4);
    int*   offs    = (int*)alloc((size_t)n * 4);
    int*   cnts    = (int*)alloc((size_t)n * 4);
    float* inv     = (float*)alloc((size_t)n * 4);
    int*   ssrc    = (int*)alloc((size_t)e * 4);
    float* bufA    = (float*)alloc((size_t)n * 64 * 4);
    float* bufB    = (float*)alloc((size_t)n * 64 * 4);
    int2*  bpairs  = (int2*)bufA;   // alias: bufA unused until transforms

    hipMemsetAsync(bhist, 0, (size_t)MAXBUCK * 4, stream);

    k_bhist<<<nchunk, 256, 0, stream>>>(dst, bhist, e, nbuck);
    k_bscan<<<1, MAXBUCK, 0, stream>>>(bhist, gbase, gcursor, e, nbuck);
    k_partition<<<nchunk, 256, 0, stream>>>(src, dst, gcursor, bpairs, e, nbuck);
    k_bfin<<<nbuck, 256, 0, stream>>>(bpairs, gbase, offs, cnts, inv, ssrc, n);

    // layer 1: t' = (x@W1)*inv ; h1 = relu((sum t'[src] + t'[d])*inv[d] + b1)
    k_transform<<<1024, 256, 0, stream>>>(x, W1, inv, bufA, n);
    k_aggregate<<<2048, 256, 0, stream>>>(bufA, ssrc, offs, cnts, inv, b1, bufB, n, 1);
    // layer 2
    k_transform<<<1024, 256, 0, stream>>>(bufB, W2, inv, bufA, n);
    k_aggregate<<<2048, 256, 0, stream>>>(bufA, ssrc, offs, cnts, inv, b2, bufB, n, 1);
    // readout
    k_final<<<2048, 256, 0, stream>>>(bufB, Wl, bl, out, n);
}